// Round 9
// baseline (1072.049 us; speedup 1.0000x reference)
//
#include <hip/hip_runtime.h>

// 2-layer GRU (B=1024, T=512, F=128, H=64) + ReLU + FC(64->18), fp32 in/out.
//
// R12 = R10/R11 resubmitted (third attempt; prior two were container
// failures with the cold-push-timeout signature, not kernel verdicts).
// Deadlock audit: all barriers uniform; ring/lag dataflow re-verified
// line-by-line (P invariant xf32=x(t+2), L0 pre-read slot (t+1)&3,
// L1 lag-2 parity, no slot races, finite loops). Pre-committed rule:
// if this also infra-fails, R10's structure is abandoned next round.
//
// R10 = R9 (operand-swapped MFMA, pre-scaled gates, packed b64 h-writes)
// + dependency restructure: move every movable LDS read / MFMA off the
// post-barrier critical path. Evidence: R8 (no vmcnt drain) and R9
// (-12% instructions) were both time-neutral at 483us -> tick is bound by
// the post-barrier latency chain, not issue count or drain.
//  1. gx ring depth 4, P produces gx(t+2) at tick t -> L0 PRE-reads gx for
//     tick t+1 at the end of tick t (slot written at t-1, barrier-ordered).
//  2. L1 lags 2 ticks: at tick t it computes h1(t-2); during tick t it
//     PRE-reads h0(t-1) and PRE-computes the 6 gx1 MFMAs into registers.
//  3. All post-barrier MFMA chains are 2-deep (hh only) + f32x4 add.
//
// 64 blocks x 768 threads (12 waves, 3/SIMD), one block per 16-row tile:
//   waves 0-3  (P):  gx(t+2) -> 4-slot LDS ring, f32 (ch,batch) C-layout.
//   waves 4-7  (L0): h0(t) = GRUcell(gx(t)[pre-read], h0(t-1))
//   waves 8-11 (L1): h1(t-2) = GRUcell(gx1(t-2)[pre-computed], h1(t-3))
// One __syncthreads per tick; loop runs Tn+2 ticks (lag-2 epilogue).

#define Tn 512
#define Fn 128
#define Hn 64
#define An 18
#define HS 72        // padded h row stride (halves): 144B rows

#define S_RZ (-1.4426950408889634f)
#define S_N  (-2.8853900817779268f)

typedef _Float16 half8 __attribute__((ext_vector_type(8)));
typedef _Float16 half4 __attribute__((ext_vector_type(4)));
typedef float f32x4 __attribute__((ext_vector_type(4)));

// Operand-swapped: A = weights, B = x/h fragments. C output = (channel, batch).
#define MFMA(w, d, c) __builtin_amdgcn_mfma_f32_16x16x32_f16((w), (d), (c), 0, 0, 0)

// Inputs pre-scaled by S_RZ / S_N at weight-load time.
static __device__ __forceinline__ float sigm_s(float x) {
    return __builtin_amdgcn_rcpf(1.0f + __builtin_amdgcn_exp2f(x));
}
static __device__ __forceinline__ float tanh_s(float x) {
    return 2.0f * __builtin_amdgcn_rcpf(1.0f + __builtin_amdgcn_exp2f(x)) - 1.0f;
}

__global__ __launch_bounds__(768) void gru_fused(
    const float* __restrict__ state,
    const float* __restrict__ Wih0, const float* __restrict__ Whh0,
    const float* __restrict__ bih0, const float* __restrict__ bhh0,
    const float* __restrict__ Wih1, const float* __restrict__ Whh1,
    const float* __restrict__ bih1, const float* __restrict__ bhh1,
    const float* __restrict__ fcw, const float* __restrict__ fcb,
    float* __restrict__ out)
{
    const int tid  = threadIdx.x;
    const int wv12 = tid >> 6;
    const int lane = tid & 63, c = lane & 15, q = lane >> 4;
    const int wv   = wv12 & 3;
    const int r0   = blockIdx.x * 16;
    const int gc   = wv * 16 + c;        // A-frag row (channel) for W loads
    const int cb   = wv * 16 + q * 4;    // C-output channel base
    const int role = (wv12 < 4) ? 0 : (wv12 < 8 ? 1 : 2);

    __shared__ __align__(16) float    gxring[4][4][3][64][4];   // 48 KiB
    __shared__ __align__(16) _Float16 h0buf[2][16 * HS];        // 4.5 KiB
    __shared__ __align__(16) _Float16 h1buf[2][16 * HS];        // 4.5 KiB
    __shared__ float fbuf[16 * 64];                             // 4 KiB

    for (int i = tid; i < 2 * 16 * HS; i += 768) {
        (&h0buf[0][0])[i] = (_Float16)0.0f;
        (&h1buf[0][0])[i] = (_Float16)0.0f;
    }

    // Weight fragments (A-operand; pre-scaled):
    //  P : W[gsel*4+ks] = Wih0~ (k=128, 4 ksteps)
    //  L0: W[gsel*2+ks] = Whh0~ (k=64, 2 ksteps)
    //  L1: W[gsel*2+ks] = Wih1~ ; W[6+gsel*2+ks] = Whh1~
    half8 W[12];
    f32x4 bias0, bias1, bias2, bias3;
    f32x4 xf32[8];
    f32x4 hreg = {0.f, 0.f, 0.f, 0.f};
    const f32x4 z4 = {0.f, 0.f, 0.f, 0.f};
    f32x4 gxp0 = z4, gxp1 = z4, gxp2 = z4;   // L0: pre-read gx for next tick
    f32x4 gxa0 = z4, gxa1 = z4, gxa2 = z4;   // L1: pre-computed gx1 for next tick
    const float* srow = state + (size_t)(r0 + c) * (Tn * Fn);

    const int ardr = c * HS + q * 8;      // B-frag read base (+32 for kstep 1)
    const int wofs = c * HS + cb;         // packed b64 h-write offset

    if (role == 0) {
#pragma unroll
        for (int gsel = 0; gsel < 3; ++gsel) {
            const float s = (gsel < 2) ? S_RZ : S_N;
            const int g = gsel * 64 + gc;
#pragma unroll
            for (int ks = 0; ks < 4; ++ks) {
                const float* p = Wih0 + g * Fn + ks * 32 + q * 8;
#pragma unroll
                for (int j = 0; j < 8; ++j) W[gsel * 4 + ks][j] = (_Float16)(s * p[j]);
            }
        }
        {
            const f32x4 bi0 = *(const f32x4*)&bih0[cb]      , bh0 = *(const f32x4*)&bhh0[cb];
            const f32x4 bi1 = *(const f32x4*)&bih0[64 + cb] , bh1 = *(const f32x4*)&bhh0[64 + cb];
            bias0 = (bi0 + bh0) * S_RZ;
            bias1 = (bi1 + bh1) * S_RZ;
            bias2 = (*(const f32x4*)&bih0[128 + cb]) * S_N;
        }
        // -------- prologue: gx(0)->slot0, gx(1)->slot1; preload x(2) --------
#pragma unroll
        for (int tt = 0; tt < 2; ++tt) {
#pragma unroll
            for (int ks = 0; ks < 4; ++ks) {
                xf32[2 * ks]     = *(const f32x4*)(srow + tt * Fn + ks * 32 + q * 8);
                xf32[2 * ks + 1] = *(const f32x4*)(srow + tt * Fn + ks * 32 + q * 8 + 4);
            }
            half8 xf[4];
#pragma unroll
            for (int ks = 0; ks < 4; ++ks)
#pragma unroll
                for (int i = 0; i < 4; ++i) {
                    xf[ks][i]     = (_Float16)xf32[2 * ks][i];
                    xf[ks][4 + i] = (_Float16)xf32[2 * ks + 1][i];
                }
            f32x4 a0 = bias0, a1 = bias1, a2 = bias2;
#pragma unroll
            for (int ks = 0; ks < 4; ++ks) {
                a0 = MFMA(W[ks],     xf[ks], a0);
                a1 = MFMA(W[4 + ks], xf[ks], a1);
                a2 = MFMA(W[8 + ks], xf[ks], a2);
            }
            *(f32x4*)&gxring[tt][wv][0][lane][0] = a0;
            *(f32x4*)&gxring[tt][wv][1][lane][0] = a1;
            *(f32x4*)&gxring[tt][wv][2][lane][0] = a2;
        }
#pragma unroll
        for (int ks = 0; ks < 4; ++ks) {
            xf32[2 * ks]     = *(const f32x4*)(srow + 2 * Fn + ks * 32 + q * 8);
            xf32[2 * ks + 1] = *(const f32x4*)(srow + 2 * Fn + ks * 32 + q * 8 + 4);
        }
    } else if (role == 1) {
#pragma unroll
        for (int gsel = 0; gsel < 3; ++gsel) {
            const float s = (gsel < 2) ? S_RZ : S_N;
            const int g = gsel * 64 + gc;
#pragma unroll
            for (int ks = 0; ks < 2; ++ks) {
                const float* p = Whh0 + g * Hn + ks * 32 + q * 8;
#pragma unroll
                for (int j = 0; j < 8; ++j) W[gsel * 2 + ks][j] = (_Float16)(s * p[j]);
            }
        }
        bias3 = (*(const f32x4*)&bhh0[128 + cb]) * S_N;
    } else {
#pragma unroll
        for (int gsel = 0; gsel < 3; ++gsel) {
            const float s = (gsel < 2) ? S_RZ : S_N;
            const int g = gsel * 64 + gc;
#pragma unroll
            for (int ks = 0; ks < 2; ++ks) {
                const float* pa = Wih1 + g * Hn + ks * 32 + q * 8;
                const float* pb = Whh1 + g * Hn + ks * 32 + q * 8;
#pragma unroll
                for (int j = 0; j < 8; ++j) {
                    W[gsel * 2 + ks][j]     = (_Float16)(s * pa[j]);
                    W[6 + gsel * 2 + ks][j] = (_Float16)(s * pb[j]);
                }
            }
        }
        const f32x4 bi0 = *(const f32x4*)&bih1[cb]      , bh0 = *(const f32x4*)&bhh1[cb];
        const f32x4 bi1 = *(const f32x4*)&bih1[64 + cb] , bh1 = *(const f32x4*)&bhh1[64 + cb];
        bias0 = (bi0 + bh0) * S_RZ;
        bias1 = (bi1 + bh1) * S_RZ;
        bias2 = (*(const f32x4*)&bih1[128 + cb]) * S_N;
        bias3 = (*(const f32x4*)&bhh1[128 + cb]) * S_N;
    }

    __syncthreads();
    // L0 pre-reads gx(0) (written in P's prologue) before the loop.
    if (role == 1) {
        gxp0 = *(const f32x4*)&gxring[0][wv][0][lane][0];
        gxp1 = *(const f32x4*)&gxring[0][wv][1][lane][0];
        gxp2 = *(const f32x4*)&gxring[0][wv][2][lane][0];
    }

    // Tick t: P makes gx(t+2) (t<=Tn-3); L0 makes h0(t) (t<Tn);
    //         L1 makes h1(t-2) (t>=2) and pre-computes gx1 for t+1 (1<=t<=Tn).
    for (int t = 0; t <= Tn + 1; ++t) {
        __syncthreads();
        if (role == 0) {
            if (t <= Tn - 3) {
                half8 xf[4];
#pragma unroll
                for (int ks = 0; ks < 4; ++ks)
#pragma unroll
                    for (int i = 0; i < 4; ++i) {
                        xf[ks][i]     = (_Float16)xf32[2 * ks][i];
                        xf[ks][4 + i] = (_Float16)xf32[2 * ks + 1][i];
                    }
                if (t <= Tn - 4) {
                    const int tnx = t + 3;
#pragma unroll
                    for (int ks = 0; ks < 4; ++ks) {
                        xf32[2 * ks]     = *(const f32x4*)(srow + (size_t)tnx * Fn + ks * 32 + q * 8);
                        xf32[2 * ks + 1] = *(const f32x4*)(srow + (size_t)tnx * Fn + ks * 32 + q * 8 + 4);
                    }
                }
                f32x4 a0 = bias0, a1 = bias1, a2 = bias2;
#pragma unroll
                for (int ks = 0; ks < 4; ++ks) {
                    a0 = MFMA(W[ks],     xf[ks], a0);
                    a1 = MFMA(W[4 + ks], xf[ks], a1);
                    a2 = MFMA(W[8 + ks], xf[ks], a2);
                }
                const int slot = (t + 2) & 3;
                *(f32x4*)&gxring[slot][wv][0][lane][0] = a0;
                *(f32x4*)&gxring[slot][wv][1][lane][0] = a1;
                *(f32x4*)&gxring[slot][wv][2][lane][0] = a2;
            }
        } else if (role == 1) {
            if (t < Tn) {
                // post-barrier critical path: h0(t-1) read + 2-deep hh MFMA
                const int pr = (t + 1) & 1, pw = t & 1;
                const half8 hf0 = *(const half8*)&h0buf[pr][ardr];
                const half8 hf1 = *(const half8*)&h0buf[pr][ardr + 32];
                f32x4 hr = MFMA(W[0], hf0, z4);    hr = MFMA(W[1], hf1, hr);
                f32x4 hz = MFMA(W[2], hf0, z4);    hz = MFMA(W[3], hf1, hz);
                f32x4 hn = MFMA(W[4], hf0, bias3); hn = MFMA(W[5], hf1, hn);
                const f32x4 accr = gxp0 + hr;
                const f32x4 accz = gxp1 + hz;
                half4 hw;
#pragma unroll
                for (int i = 0; i < 4; ++i) {
                    const float rg = sigm_s(accr[i]);
                    const float zg = sigm_s(accz[i]);
                    const float ng = tanh_s(gxp2[i] + rg * hn[i]);
                    hreg[i] = ng + zg * (hreg[i] - ng);
                    hw[i] = (_Float16)hreg[i];
                }
                *(half4*)&h0buf[pw][wofs] = hw;
                // pre-read gx(t+1) for next tick (slot written at t-1)
                if (t + 1 < Tn) {
                    const int ns = (t + 1) & 3;
                    gxp0 = *(const f32x4*)&gxring[ns][wv][0][lane][0];
                    gxp1 = *(const f32x4*)&gxring[ns][wv][1][lane][0];
                    gxp2 = *(const f32x4*)&gxring[ns][wv][2][lane][0];
                }
            }
        } else {
            if (t >= 2) {
                // post-barrier critical path: h1(t-3) read + 2-deep hh MFMA
                const half8 hf0 = *(const half8*)&h1buf[(t + 1) & 1][ardr];
                const half8 hf1 = *(const half8*)&h1buf[(t + 1) & 1][ardr + 32];
                f32x4 hr = MFMA(W[6], hf0, z4);     hr = MFMA(W[7], hf1, hr);
                f32x4 hz = MFMA(W[8], hf0, z4);     hz = MFMA(W[9], hf1, hz);
                f32x4 hn = MFMA(W[10], hf0, bias3); hn = MFMA(W[11], hf1, hn);
                const f32x4 accr = gxa0 + hr;
                const f32x4 accz = gxa1 + hz;
                half4 hw;
#pragma unroll
                for (int i = 0; i < 4; ++i) {
                    const float rg = sigm_s(accr[i]);
                    const float zg = sigm_s(accz[i]);
                    const float ng = tanh_s(gxa2[i] + rg * hn[i]);
                    hreg[i] = ng + zg * (hreg[i] - ng);
                    hw[i] = (_Float16)hreg[i];
                }
                *(half4*)&h1buf[t & 1][wofs] = hw;
            }
            if (t >= 1 && t <= Tn) {
                // pre-compute gx1 for next tick: h0(t-1) written at t-1,
                // ordered by this tick's barrier.
                const half8 xf0 = *(const half8*)&h0buf[(t + 1) & 1][ardr];
                const half8 xf1 = *(const half8*)&h0buf[(t + 1) & 1][ardr + 32];
                gxa0 = MFMA(W[0], xf0, bias0); gxa0 = MFMA(W[1], xf1, gxa0);
                gxa1 = MFMA(W[2], xf0, bias1); gxa1 = MFMA(W[3], xf1, gxa1);
                gxa2 = MFMA(W[4], xf0, bias2); gxa2 = MFMA(W[5], xf1, gxa2);
            }
        }
    }

    // epilogue: relu(h1(Tn-1)) @ fc3_w.T + fc3_b  (L1 holds (batch c, ch cb..cb+3))
    if (role == 2) {
        f32x4 fv;
#pragma unroll
        for (int i = 0; i < 4; ++i) fv[i] = fmaxf(hreg[i], 0.0f);
        *(f32x4*)&fbuf[c * 64 + cb] = fv;
    }
    __syncthreads();
    for (int idx = tid; idx < 16 * An; idx += 768) {
        const int row = idx / An, a = idx - row * An;
        float acc = fcb[a];
#pragma unroll 16
        for (int k = 0; k < Hn; ++k) acc += fbuf[row * 64 + k] * fcw[a * Hn + k];
        out[(size_t)(r0 + row) * An + a] = acc;
    }
}

extern "C" void kernel_launch(void* const* d_in, const int* in_sizes, int n_in,
                              void* d_out, int out_size, void* d_ws, size_t ws_size,
                              hipStream_t stream) {
    const float* state = (const float*)d_in[0];
    const float* Wih0  = (const float*)d_in[1];
    const float* Whh0  = (const float*)d_in[2];
    const float* bih0  = (const float*)d_in[3];
    const float* bhh0  = (const float*)d_in[4];
    const float* Wih1  = (const float*)d_in[5];
    const float* Whh1  = (const float*)d_in[6];
    const float* bih1  = (const float*)d_in[7];
    const float* bhh1  = (const float*)d_in[8];
    const float* fcw   = (const float*)d_in[9];
    const float* fcb   = (const float*)d_in[10];
    float* out = (float*)d_out;

    gru_fused<<<64, 768, 0, stream>>>(state, Wih0, Whh0, bih0, bhh0,
                                      Wih1, Whh1, bih1, bhh1, fcw, fcb, out);
}